// Round 2
// baseline (794.386 us; speedup 1.0000x reference)
//
#include <hip/hip_runtime.h>
#include <math.h>
#include <stdint.h>

// VQActivation residual VQ, depth=4. x:(32,256,56,56) f32, cb:(1024,256) f32.
//
// PASSED semantics preserved exactly: decisions = np f32 sgemm = sequential
// fmaf chain over k ascending, single f32 accumulator; u = that bitwise max;
// resid -= fl(cb*u) with separate roundings; out re-summed in np's exact
// f32 add order. Candidate SELECTION (bf16-MFMA approx) only needs to
// CONTAIN the exact winner; Phase B re-ranks candidates with the exact chain.
//
// Round-4 (this round): occupancy 3->4 blocks/CU + selection VALU cut:
//   * candidates tracked as packed u32 sort keys:
//       key = ((bits(ip) ^ 0x80000000) & 0xFFFFFC00) | (1023 - code)
//     monotone-enough ordering (negatives all rank below positives; 22 value
//     bits ~ 1.2e-4 rel quantization << bf16 approx error 1.6e-3).
//     Top-k maintenance = pure v_min_u32/v_max_u32 networks (no vcc chains),
//     half the shuffles, and halves candidate LDS.
//   * LDS = resid 33,280 + entK 6,144 + u_all 1,024 + c_all 512 = 40,960 B
//     = 160 KiB / 4  ->  4 blocks/CU (was 3).

#define KDIM 256
#define KSZ  1024
#define TM   32
#define HWSZ 3136
#define NBLK (HWSZ/TM)   // 98 row-blocks per image
#define RSTR 260         // resid row stride (f32): 16B-aligned, bank-skewed
#define MAXD 8           // harness depth is 4; 8 gives slack at zero LDS cost risk

using f32x4  = __attribute__((ext_vector_type(4))) float;
using bf16x8 = __attribute__((ext_vector_type(8))) short;

static __device__ __forceinline__ unsigned short f2bf(float f) {
    unsigned u = __float_as_uint(f);
    u += 0x7fffu + ((u >> 16) & 1u);
    return (unsigned short)(u >> 16);
}

static __device__ __forceinline__ unsigned umax(unsigned a, unsigned b) { return a > b ? a : b; }
static __device__ __forceinline__ unsigned umin(unsigned a, unsigned b) { return a < b ? a : b; }

// 8 f32 -> 8 bf16 via 4x v_cvt_pk_bf16_f32 (lo = first operand, RNE).
static __device__ __forceinline__ bf16x8 pk8(const float4 a, const float4 b) {
    union { unsigned u[4]; bf16x8 v; } r;
    asm("v_cvt_pk_bf16_f32 %0, %1, %2" : "=v"(r.u[0]) : "v"(a.x), "v"(a.y));
    asm("v_cvt_pk_bf16_f32 %0, %1, %2" : "=v"(r.u[1]) : "v"(a.z), "v"(a.w));
    asm("v_cvt_pk_bf16_f32 %0, %1, %2" : "=v"(r.u[2]) : "v"(b.x), "v"(b.y));
    asm("v_cvt_pk_bf16_f32 %0, %1, %2" : "=v"(r.u[3]) : "v"(b.z), "v"(b.w));
    return r.v;
}

// insert key into sorted-desc (q1>=q2>=q3>=q4): 7 min/max ops
static __device__ __forceinline__ void insk4(unsigned k,
    unsigned& q1, unsigned& q2, unsigned& q3, unsigned& q4) {
    unsigned t1 = umin(q1, k); q1 = umax(q1, k);
    unsigned t2 = umin(q2, t1); q2 = umax(q2, t1);
    unsigned t3 = umin(q3, t2); q3 = umax(q3, t2);
    q4 = umax(q4, t3);
}

// ---- pack cb f32 [1024][256] into MFMA-B-fragment-native bf16 (512 KB) ----
// frag f = (tg*8 + kt)*64 + lane ; lane = n + 16*q holds
// cb[tg*16+n][kt*32 + q*8 + 0..7] as 8 bf16 (16 B).
__global__ __launch_bounds__(256)
void make_cb_frag(const float* __restrict__ cb, bf16x8* __restrict__ cbf)
{
    const int f    = blockIdx.x * 256 + threadIdx.x;   // 0..32767
    const int lane = f & 63, kt = (f >> 6) & 7, tg = f >> 9;
    const int n = lane & 15, q = lane >> 4;
    const float* src = cb + ((size_t)(tg * 16 + n)) * KDIM + kt * 32 + q * 8;
    const float4 a = ((const float4*)src)[0];
    const float4 b = ((const float4*)src)[1];
    bf16x8 s;
    s[0] = (short)f2bf(a.x); s[1] = (short)f2bf(a.y);
    s[2] = (short)f2bf(a.z); s[3] = (short)f2bf(a.w);
    s[4] = (short)f2bf(b.x); s[5] = (short)f2bf(b.y);
    s[6] = (short)f2bf(b.z); s[7] = (short)f2bf(b.w);
    cbf[f] = s;
}

__global__ __launch_bounds__(256, 4)
void vq_kernel(const float* __restrict__ x,
               const float* __restrict__ cb,
               const bf16x8* __restrict__ cbf,
               const int*   __restrict__ depth_p,
               float*       __restrict__ out)
{
    __shared__ __align__(16) float resid[TM][RSTR];     // 33,280 B
    __shared__ __align__(16) unsigned entK[TM][4][12];  //  6,144 B
    __shared__ float          u_all[MAXD][TM];          //  1,024 B
    __shared__ unsigned short c_all[MAXD][TM];          //    512 B
                                                        // = 40,960 = 160K/4

    const int tid  = threadIdx.x;
    const int bidx = blockIdx.x;
    const int b    = bidx / NBLK;
    const int hw0  = (bidx % NBLK) * TM;
    const int depth = depth_p[0];
    const int lane = tid & 63, w = tid >> 6;     // wave w = code quarter
    const int n = lane & 15, q = lane >> 4;
    const int wbase = w * 256;

    // ---- stage x -> resid (coalesced along hw) ----
    {
        const int r = tid & 31, ks = tid >> 5;
        const float* xp = x + ((size_t)b * KDIM + ks * 32) * HWSZ + hw0 + r;
        for (int m = 0; m < 32; ++m)
            resid[r][ks * 32 + m] = xp[(size_t)m * HWSZ];
    }
    __syncthreads();

    const bf16x8* bp0 = cbf + (size_t)w * 8192 + lane;

    for (int d = 0; d < depth; ++d) {
        // ---- issue first B-tile loads early (latency hides under cvt) ----
        bf16x8 bA[8], bB[8];
#pragma unroll
        for (int kt = 0; kt < 8; ++kt) bA[kt] = bp0[kt * 64];

        // ---- A-fragments (bf16) via packed converts: rows 0..15, 16..31 ----
        bf16x8 fa0[8], fa1[8];
#pragma unroll
        for (int kt = 0; kt < 8; ++kt) {
            const float* s0 = &resid[n][kt * 32 + q * 8];
            const float* s1 = &resid[16 + n][kt * 32 + q * 8];
            fa0[kt] = pk8(((const float4*)s0)[0], ((const float4*)s0)[1]);
            fa1[kt] = pk8(((const float4*)s1)[0], ((const float4*)s1)[1]);
        }

        // ---- MFMA GEMM over this wave's 256 codes + per-lane top-2 keys ----
        unsigned k1[8], k2[8];
#pragma unroll
        for (int e = 0; e < 8; ++e) { k1[e] = 0u; k2[e] = 0u; }

#define MFMA_SELECT(BB, I)                                                        \
        {                                                                         \
            f32x4 A0 = {0.f, 0.f, 0.f, 0.f};                                      \
            f32x4 A1 = {0.f, 0.f, 0.f, 0.f};                                      \
            _Pragma("unroll")                                                     \
            for (int kt = 0; kt < 8; ++kt) {                                      \
                A0 = __builtin_amdgcn_mfma_f32_16x16x32_bf16(fa0[kt], BB[kt], A0, 0, 0, 0); \
                A1 = __builtin_amdgcn_mfma_f32_16x16x32_bf16(fa1[kt], BB[kt], A1, 0, 0, 0); \
            }                                                                     \
            const unsigned rc = (unsigned)(1023 - (wbase + (I) * 16 + n));        \
            _Pragma("unroll")                                                     \
            for (int e = 0; e < 4; ++e) {                                         \
                {                                                                 \
                    const unsigned kk = ((__float_as_uint(A0[e]) ^ 0x80000000u)   \
                                         & 0xFFFFFC00u) | rc;                     \
                    const unsigned t = umin(k1[e], kk);                           \
                    k1[e] = umax(k1[e], kk);                                      \
                    k2[e] = umax(k2[e], t);                                       \
                }                                                                 \
                {                                                                 \
                    const unsigned kk = ((__float_as_uint(A1[e]) ^ 0x80000000u)   \
                                         & 0xFFFFFC00u) | rc;                     \
                    const unsigned t = umin(k1[4+e], kk);                         \
                    k1[4+e] = umax(k1[4+e], kk);                                  \
                    k2[4+e] = umax(k2[4+e], t);                                   \
                }                                                                 \
            }                                                                     \
        }

        for (int ii = 0; ii < 8; ++ii) {
            const bf16x8* bpB = bp0 + (size_t)(2 * ii + 1) * 512;
#pragma unroll
            for (int kt = 0; kt < 8; ++kt) bB[kt] = bpB[kt * 64];
            MFMA_SELECT(bA, 2 * ii);
            if (ii < 7) {
                const bf16x8* bpA = bp0 + (size_t)(2 * ii + 2) * 512;
#pragma unroll
                for (int kt = 0; kt < 8; ++kt) bA[kt] = bpA[kt * 64];
            }
            MFMA_SELECT(bB, 2 * ii + 1);
        }
#undef MFMA_SELECT

        // ---- extend to top-3, merge across lane pairs (xor 1, xor 2) ----
        unsigned k3[8];
#pragma unroll
        for (int e = 0; e < 8; ++e) k3[e] = 0u;
#pragma unroll
        for (int m = 1; m <= 2; m <<= 1) {
#pragma unroll
            for (int e = 0; e < 8; ++e) {
                const unsigned o1 = __shfl_xor(k1[e], m, 64);
                const unsigned o2 = __shfl_xor(k2[e], m, 64);
                const unsigned o3 = __shfl_xor(k3[e], m, 64);
                const unsigned a1 = k1[e], a2 = k2[e], a3 = k3[e];
                // top-3 of merge of sorted triples: 9-op min/max network
                k1[e] = umax(a1, o1);
                k2[e] = umax(umin(a1, o1), umax(a2, o2));
                k3[e] = umax(umax(a3, o3), umax(umin(a2, o1), umin(a1, o2)));
            }
        }
        if ((n & 3) == 0) {
            const int g = n >> 2;
#pragma unroll
            for (int e = 0; e < 8; ++e) {
                const int row = (e < 4) ? (q * 4 + e) : (16 + q * 4 + (e - 4));
                entK[row][w][g * 3 + 0] = k1[e];
                entK[row][w][g * 3 + 1] = k2[e];
                entK[row][w][g * 3 + 2] = k3[e];
            }
        }
        __syncthreads();

        // ---- Phase B: per-row top-4 candidates + EXACT np-bitwise re-rank ----
        if (tid < 128) {
            const int row = tid >> 2, j = tid & 3;
            const uint4* ep = (const uint4*)&entK[row][j][0];
            const uint4 Ea = ep[0], Eb = ep[1], Ec = ep[2];
            unsigned q1 = 0u, q2 = 0u, q3 = 0u, q4 = 0u;
            insk4(Ea.x, q1, q2, q3, q4); insk4(Ea.y, q1, q2, q3, q4);
            insk4(Ea.z, q1, q2, q3, q4); insk4(Ea.w, q1, q2, q3, q4);
            insk4(Eb.x, q1, q2, q3, q4); insk4(Eb.y, q1, q2, q3, q4);
            insk4(Eb.z, q1, q2, q3, q4); insk4(Eb.w, q1, q2, q3, q4);
            insk4(Ec.x, q1, q2, q3, q4); insk4(Ec.y, q1, q2, q3, q4);
            insk4(Ec.z, q1, q2, q3, q4); insk4(Ec.w, q1, q2, q3, q4);
#pragma unroll
            for (int m = 1; m <= 2; m <<= 1) {
                const unsigned o1 = __shfl_xor(q1, m, 64);
                const unsigned o2 = __shfl_xor(q2, m, 64);
                const unsigned o3 = __shfl_xor(q3, m, 64);
                const unsigned o4 = __shfl_xor(q4, m, 64);
                insk4(o1, q1, q2, q3, q4); insk4(o2, q1, q2, q3, q4);
                insk4(o3, q1, q2, q3, q4); insk4(o4, q1, q2, q3, q4);
            }
            const unsigned sel = (j == 0) ? q1 : (j == 1) ? q2 : (j == 2) ? q3 : q4;
            const int cand = 1023 - (int)(sel & 0x3FFu);

            // exact np f32 chain: ascending k, single accumulator (passing semantics)
            float e = 0.f;
            const float4* cbr = (const float4*)(cb + (size_t)cand * KDIM);
            const float4* rr  = (const float4*)(&resid[row][0]);
#pragma unroll 4
            for (int kk = 0; kk < 64; ++kk) {
                const float4 cv = cbr[kk];
                const float4 rv = rr[kk];
                e = fmaf(rv.x, cv.x, e); e = fmaf(rv.y, cv.y, e);
                e = fmaf(rv.z, cv.z, e); e = fmaf(rv.w, cv.w, e);
            }
            float be = e; int bc = cand;
#pragma unroll
            for (int m = 1; m <= 2; m <<= 1) {
                const float oe = __shfl_xor(be, m, 64);
                const int   oc = __shfl_xor(bc, m, 64);
                if (oe > be || (oe == be && oc < bc)) { be = oe; bc = oc; }
            }
            if (j == 0) { u_all[d][row] = be; c_all[d][row] = (unsigned short)bc; }
        }
        __syncthreads();

        // ---- Phase C: resid = fl(resid - fl(cb[cw]*u))  (bitwise np) ----
        {
            const int row = tid >> 3, t8 = tid & 7;
            const float uu = u_all[d][row];
            const float* cr = cb + (size_t)c_all[d][row] * KDIM;
#pragma unroll
            for (int jj = 0; jj < 8; ++jj) {
                const int k = t8 * 4 + jj * 32;
                const float4 cv = *(const float4*)(cr + k);
                resid[row][k + 0] = __fsub_rn(resid[row][k + 0], __fmul_rn(cv.x, uu));
                resid[row][k + 1] = __fsub_rn(resid[row][k + 1], __fmul_rn(cv.y, uu));
                resid[row][k + 2] = __fsub_rn(resid[row][k + 2], __fmul_rn(cv.z, uu));
                resid[row][k + 3] = __fsub_rn(resid[row][k + 3], __fmul_rn(cv.w, uu));
            }
        }
        __syncthreads();
    }

    // ---- out = ((comp1+comp2)+comp3)+comp4, np's exact elementwise order ----
    {
        const int r = tid & 31, ks = tid >> 5;
        float* op = out + ((size_t)b * KDIM + ks * 32) * HWSZ + hw0 + r;
#pragma unroll
        for (int jj = 0; jj < 8; ++jj) {
            float ax = 0.f, ay = 0.f, az = 0.f, aw = 0.f;
            for (int d = 0; d < depth; ++d) {
                const float uu = u_all[d][r];
                const float* cr = cb + (size_t)c_all[d][r] * KDIM + ks * 32 + jj * 4;
                const float4 cv = *(const float4*)cr;
                ax = __fadd_rn(ax, __fmul_rn(cv.x, uu));
                ay = __fadd_rn(ay, __fmul_rn(cv.y, uu));
                az = __fadd_rn(az, __fmul_rn(cv.z, uu));
                aw = __fadd_rn(aw, __fmul_rn(cv.w, uu));
            }
            op[(size_t)(jj * 4 + 0) * HWSZ] = ax;
            op[(size_t)(jj * 4 + 1) * HWSZ] = ay;
            op[(size_t)(jj * 4 + 2) * HWSZ] = az;
            op[(size_t)(jj * 4 + 3) * HWSZ] = aw;
        }
    }
}

extern "C" void kernel_launch(void* const* d_in, const int* in_sizes, int n_in,
                              void* d_out, int out_size, void* d_ws, size_t ws_size,
                              hipStream_t stream)
{
    const float* x     = (const float*)d_in[0];
    const float* cb    = (const float*)d_in[1];
    const int*   depth = (const int*)d_in[2];
    float*       out   = (float*)d_out;
    bf16x8*      cbf   = (bf16x8*)d_ws;   // 512 KB fragment-packed bf16 codebook

    hipLaunchKernelGGL(make_cb_frag, dim3(128), dim3(256), 0, stream, cb, cbf);

    const int N      = in_sizes[0] / KDIM;  // 100352 pixel rows
    const int nblock = N / TM;              // 3136
    hipLaunchKernelGGL(vq_kernel, dim3(nblock), dim3(256), 0, stream,
                       x, cb, cbf, depth, out);
}